// Round 8
// baseline (125.249 us; speedup 1.0000x reference)
//
#include <hip/hip_runtime.h>

// Tiny ViT forward, B=8192, fp32. 512-thread block = 10 images x 50
// tokens, ONE LANE PER (image, token): 500/512 lanes active (97.6%).
// Scalar math throughout (fp32 ALU-cycle-bound; packed fp32 saves only
// issue slots, not ALU cycles). K/V in block LDS (stride-padded, reads
// are 2-3-way broadcast = free), 2 barriers per transformer block.
// Weights via wave-uniform global loads (s_load path). One-pass softmax
// without max subtraction (scores ~0.06 std; exp-safe).

#define T_TOK     50
#define IMGS_PB   10
#define THREADS   512
#define KVSTRIDE  20                 // floats per token: 16 + 4 pad
#define IMG_STRIDE (T_TOK * KVSTRIDE)   // 1000 floats
#define SCALE     0.35355339059327373f  // 8^-0.5

#if __has_builtin(__builtin_amdgcn_exp2f)
  #define FASTEXP(x) __builtin_amdgcn_exp2f(x)
  #define QSCALE (SCALE * 1.4426950408889634f)   // fold log2(e) into q
#else
  #define FASTEXP(x) __expf(x)
  #define QSCALE SCALE
#endif

__global__ __launch_bounds__(THREADS) void vit_fwd(
    const float* __restrict__ images, const float* __restrict__ cls,
    const float* __restrict__ linW,
    const float* __restrict__ g1,  const float* __restrict__ be1,
    const float* __restrict__ Wq,  const float* __restrict__ Wk,
    const float* __restrict__ Wv,  const float* __restrict__ Pw,
    const float* __restrict__ Pb,  const float* __restrict__ g2,
    const float* __restrict__ be2, const float* __restrict__ W1,
    const float* __restrict__ bb1, const float* __restrict__ W2,
    const float* __restrict__ bb2, const float* __restrict__ mlpW,
    const float* __restrict__ mlpb,
    float* __restrict__ out, int B)
{
    __shared__ float kv[IMGS_PB * IMG_STRIDE];   // 40000 B

    const int tid  = threadIdx.x;
    const int img  = tid / T_TOK;          // 0..9 (10 for tid>=500)
    const int t    = tid - img * T_TOK;    // token 0..49
    const int gimg = blockIdx.x * IMGS_PB + img;
    const bool active = (img < IMGS_PB) && (gimg < B);
    float* __restrict__ kvi = kv + img * IMG_STRIDE;

    // ---- patch embed + positional ----
    float x[8];
    if (active) {
        const float FR[4] = {1.f, 0.1f, 0.01f, 0.001f};
        float pos[8];
        #pragma unroll
        for (int j = 0; j < 8; ++j) {
            float arg = (float)t * FR[j >> 1];
            pos[j] = (j & 1) ? __cosf(arg) : __sinf(arg);
        }
        if (t == 0) {
            #pragma unroll
            for (int e = 0; e < 8; ++e) x[e] = cls[e] + pos[e];
        } else {
            const int p = t - 1, pr = p / 7, pc = p - pr * 7;
            const float* ib = images + (size_t)gimg * 784 + pr * 112 + pc * 4;
            float pf[16];
            #pragma unroll
            for (int r = 0; r < 4; ++r) {
                float4 u = *reinterpret_cast<const float4*>(ib + r * 28);
                pf[r*4+0] = u.x; pf[r*4+1] = u.y;
                pf[r*4+2] = u.z; pf[r*4+3] = u.w;
            }
            #pragma unroll
            for (int e = 0; e < 8; ++e) {
                float a = pos[e];
                #pragma unroll
                for (int i = 0; i < 16; ++i) a += pf[i] * linW[e*16 + i];
                x[e] = a;
            }
        }
    }

    #pragma unroll 1
    for (int blk = 0; blk < 4; ++blk) {
        const int w8 = blk * 8, w64 = blk * 64, w256 = blk * 256, w32 = blk * 32;

        // ---- LN1 + q,k,v; write K/V to LDS ----
        float q[8];
        if (active) {
            float mu = 0.f;
            #pragma unroll
            for (int d = 0; d < 8; ++d) mu += x[d];
            mu *= 0.125f;
            float var = 0.f;
            #pragma unroll
            for (int d = 0; d < 8; ++d) { float dd = x[d] - mu; var += dd * dd; }
            const float rs = rsqrtf(var * 0.125f + 1e-5f);
            float h[8];
            #pragma unroll
            for (int d = 0; d < 8; ++d)
                h[d] = (x[d] - mu) * rs * g1[w8 + d] + be1[w8 + d];
            float kk[8], vv[8];
            #pragma unroll
            for (int e = 0; e < 8; ++e) {
                float aq = 0.f, ak = 0.f, av = 0.f;
                #pragma unroll
                for (int d = 0; d < 8; ++d) {
                    aq += h[d] * Wq[w64 + e*8 + d];
                    ak += h[d] * Wk[w64 + e*8 + d];
                    av += h[d] * Wv[w64 + e*8 + d];
                }
                q[e] = aq * QSCALE; kk[e] = ak; vv[e] = av;
            }
            float* kvp = kvi + t * KVSTRIDE;
            *reinterpret_cast<float4*>(kvp +  0) = make_float4(kk[0],kk[1],kk[2],kk[3]);
            *reinterpret_cast<float4*>(kvp +  4) = make_float4(kk[4],kk[5],kk[6],kk[7]);
            *reinterpret_cast<float4*>(kvp +  8) = make_float4(vv[0],vv[1],vv[2],vv[3]);
            *reinterpret_cast<float4*>(kvp + 12) = make_float4(vv[4],vv[5],vv[6],vv[7]);
        }
        __syncthreads();   // K/V visible to all waves

        if (active) {
            // ---- one-pass softmax attention (2 heads) ----
            float l0 = 0.f, l1 = 0.f;
            float a0=0.f,a1=0.f,a2=0.f,a3=0.f,a4=0.f,a5=0.f,a6=0.f,a7=0.f;
            #pragma unroll 2
            for (int s = 0; s < T_TOK; ++s) {
                const float* sp = kvi + s * KVSTRIDE;
                float4 k01 = *reinterpret_cast<const float4*>(sp +  0);
                float4 k23 = *reinterpret_cast<const float4*>(sp +  4);
                float4 v01 = *reinterpret_cast<const float4*>(sp +  8);
                float4 v23 = *reinterpret_cast<const float4*>(sp + 12);
                float d0 = q[0]*k01.x + q[1]*k01.y + q[2]*k01.z + q[3]*k01.w;
                float d1 = q[4]*k23.x + q[5]*k23.y + q[6]*k23.z + q[7]*k23.w;
                float p0 = FASTEXP(d0), p1 = FASTEXP(d1);
                l0 += p0; l1 += p1;
                a0 += p0*v01.x; a1 += p0*v01.y; a2 += p0*v01.z; a3 += p0*v01.w;
                a4 += p1*v23.x; a5 += p1*v23.y; a6 += p1*v23.z; a7 += p1*v23.w;
            }
            float o[8];
            const float r0 = 1.f / l0, r1 = 1.f / l1;
            o[0]=a0*r0; o[1]=a1*r0; o[2]=a2*r0; o[3]=a3*r0;
            o[4]=a4*r1; o[5]=a5*r1; o[6]=a6*r1; o[7]=a7*r1;

            // ---- proj + residual ----
            float xn[8];
            #pragma unroll
            for (int e = 0; e < 8; ++e) {
                float a = Pb[w8 + e];
                #pragma unroll
                for (int d = 0; d < 8; ++d) a += o[d] * Pw[w64 + e*8 + d];
                xn[e] = x[e] + a;
            }
            // ---- LN2 ----
            float mu = 0.f;
            #pragma unroll
            for (int d = 0; d < 8; ++d) mu += xn[d];
            mu *= 0.125f;
            float var = 0.f;
            #pragma unroll
            for (int d = 0; d < 8; ++d) { float dd = xn[d] - mu; var += dd * dd; }
            const float rs2 = rsqrtf(var * 0.125f + 1e-5f);
            float h2[8];
            #pragma unroll
            for (int d = 0; d < 8; ++d)
                h2[d] = (xn[d] - mu) * rs2 * g2[w8 + d] + be2[w8 + d];
            // ---- FF ----
            float acc[8] = {0.f,0.f,0.f,0.f,0.f,0.f,0.f,0.f};
            #pragma unroll 4
            for (int f = 0; f < 32; ++f) {
                float a = bb1[w32 + f];
                #pragma unroll
                for (int d = 0; d < 8; ++d) a += h2[d] * W1[w256 + f*8 + d];
                a = fmaxf(a, 0.f);
                #pragma unroll
                for (int d = 0; d < 8; ++d) acc[d] += a * W2[w256 + d*32 + f];
            }
            #pragma unroll
            for (int d = 0; d < 8; ++d) x[d] = xn[d] + acc[d] + bb2[w8 + d];
        }
        __syncthreads();   // all reads done before next iter's writes
    }

    // ---- classification head: token-0 lanes ----
    if (active && t == 0) {
        float lg[10]; float mx = -1e30f;
        #pragma unroll
        for (int c = 0; c < 10; ++c) {
            float a = mlpb[c];
            #pragma unroll
            for (int d = 0; d < 8; ++d) a += x[d] * mlpW[c*8 + d];
            lg[c] = a; mx = fmaxf(mx, a);
        }
        float ssum = 0.f;
        #pragma unroll
        for (int c = 0; c < 10; ++c) { lg[c] = __expf(lg[c] - mx); ssum += lg[c]; }
        const float rsum = 1.f / ssum;
        #pragma unroll
        for (int c = 0; c < 10; ++c)
            out[(size_t)gimg*10 + c] = lg[c] * rsum;
    }
}

extern "C" void kernel_launch(void* const* d_in, const int* in_sizes, int n_in,
                              void* d_out, int out_size, void* d_ws, size_t ws_size,
                              hipStream_t stream) {
    const int B = in_sizes[0] / 784;
    const int nblk = (B + IMGS_PB - 1) / IMGS_PB;
    vit_fwd<<<nblk, THREADS, 0, stream>>>(
        (const float*)d_in[0],  (const float*)d_in[1],  (const float*)d_in[2],
        (const float*)d_in[3],  (const float*)d_in[4],  (const float*)d_in[5],
        (const float*)d_in[6],  (const float*)d_in[7],  (const float*)d_in[8],
        (const float*)d_in[9],  (const float*)d_in[10], (const float*)d_in[11],
        (const float*)d_in[12], (const float*)d_in[13], (const float*)d_in[14],
        (const float*)d_in[15], (const float*)d_in[16], (const float*)d_in[17],
        (float*)d_out, B);
}

// Round 9
// 114.950 us; speedup vs baseline: 1.0896x; 1.0896x over previous
//
#include <hip/hip_runtime.h>

// Tiny ViT forward, B=8192, fp32. Wave-per-IMAGE-PAIR (R6 structure) +
// ILP pass: s-loop FULLY unrolled (ds_read immediate offsets, zero addr
// math) with 4 independent accumulator banks (static s&3 indexing);
// FF loop uses 2 banks. Packed fx2 math (2 images per lane) everywhere;
// per-wave LDS K/V (broadcast reads, no barriers); s_load weights.
// One-pass softmax without max subtraction (scores ~0.06 std).

typedef float fx2 __attribute__((ext_vector_type(2)));

#define T_TOK    50
#define WAVES_PB 4
#define THREADS  (WAVES_PB * 64)
#define KVSTRIDE 36                  // floats per token: 32 + 4 pad
#define SCALE    0.35355339059327373f   // 8^-0.5

#if __has_builtin(__builtin_amdgcn_exp2f)
  #define FASTEXP(x) __builtin_amdgcn_exp2f(x)
  #define QSCALE (SCALE * 1.4426950408889634f)   // fold log2(e) into q
#else
  #define FASTEXP(x) __expf(x)
  #define QSCALE SCALE
#endif

__device__ __forceinline__ fx2 bc(float s)    { return (fx2){s, s}; }
__device__ __forceinline__ fx2 lo4(float4 u)  { return (fx2){u.x, u.y}; }
__device__ __forceinline__ fx2 hi4(float4 u)  { return (fx2){u.z, u.w}; }
__device__ __forceinline__ fx2 fmax2(fx2 a, fx2 b) {
    return (fx2){fmaxf(a.x, b.x), fmaxf(a.y, b.y)};
}
__device__ __forceinline__ fx2 expboth(fx2 v) {
    return (fx2){FASTEXP(v.x), FASTEXP(v.y)};
}

__global__ __launch_bounds__(THREADS) void vit_fwd(
    const float* __restrict__ images, const float* __restrict__ cls,
    const float* __restrict__ linW,
    const float* __restrict__ g1,  const float* __restrict__ be1,
    const float* __restrict__ Wq,  const float* __restrict__ Wk,
    const float* __restrict__ Wv,  const float* __restrict__ Pw,
    const float* __restrict__ Pb,  const float* __restrict__ g2,
    const float* __restrict__ be2, const float* __restrict__ W1,
    const float* __restrict__ bb1, const float* __restrict__ W2,
    const float* __restrict__ bb2, const float* __restrict__ mlpW,
    const float* __restrict__ mlpb,
    float* __restrict__ out, int B)
{
    __shared__ float kv[WAVES_PB * T_TOK * KVSTRIDE];   // 28800 B

    const int lane = threadIdx.x & 63;
    const int wid  = threadIdx.x >> 6;
    const int pair = blockIdx.x * WAVES_PB + wid;   // wave-uniform
    const int gA   = pair * 2;
    if (gA >= B) return;
    const bool hasB = (gA + 1) < B;
    const int gB   = hasB ? gA + 1 : gA;
    const int t    = (lane < T_TOK) ? lane : (T_TOK - 1);
    float* __restrict__ kvw = kv + wid * (T_TOK * KVSTRIDE);

    // ---- patch embed + positional (pos depends only on t: shared) ----
    fx2 x[8];
    {
        const float FR[4] = {1.f, 0.1f, 0.01f, 0.001f};
        float pos[8];
        #pragma unroll
        for (int j = 0; j < 8; ++j) {
            float arg = (float)t * FR[j >> 1];
            pos[j] = (j & 1) ? __cosf(arg) : __sinf(arg);
        }
        if (t == 0) {
            #pragma unroll
            for (int e = 0; e < 8; ++e) x[e] = bc(cls[e] + pos[e]);
        } else {
            const int p = t - 1, pr = p / 7, pc = p - pr * 7;
            const size_t off = (size_t)pr * 112 + pc * 4;
            const float* ibA = images + (size_t)gA * 784 + off;
            const float* ibB = images + (size_t)gB * 784 + off;
            fx2 pf[16];
            #pragma unroll
            for (int r = 0; r < 4; ++r) {
                float4 ua = *reinterpret_cast<const float4*>(ibA + r * 28);
                float4 ub = *reinterpret_cast<const float4*>(ibB + r * 28);
                pf[r*4+0] = (fx2){ua.x, ub.x}; pf[r*4+1] = (fx2){ua.y, ub.y};
                pf[r*4+2] = (fx2){ua.z, ub.z}; pf[r*4+3] = (fx2){ua.w, ub.w};
            }
            #pragma unroll
            for (int e = 0; e < 8; ++e) {
                fx2 a = bc(pos[e]);
                #pragma unroll
                for (int i = 0; i < 16; ++i) a += pf[i] * bc(linW[e*16 + i]);
                x[e] = a;
            }
        }
    }

    #pragma unroll 1
    for (int blk = 0; blk < 4; ++blk) {
        const int w8 = blk * 8, w64 = blk * 64, w256 = blk * 256, w32 = blk * 32;

        // ---- LN1 ----
        fx2 h[8];
        {
            fx2 mu = x[0];
            #pragma unroll
            for (int d = 1; d < 8; ++d) mu += x[d];
            mu *= bc(0.125f);
            fx2 var = bc(0.f);
            #pragma unroll
            for (int d = 0; d < 8; ++d) { fx2 dd = x[d] - mu; var += dd * dd; }
            var = var * bc(0.125f) + bc(1e-5f);
            fx2 rs = {rsqrtf(var.x), rsqrtf(var.y)};
            #pragma unroll
            for (int d = 0; d < 8; ++d)
                h[d] = (x[d] - mu) * rs * bc(g1[w8 + d]) + bc(be1[w8 + d]);
        }

        // ---- q,k,v: packed pk_fma chains (SGPR-broadcast weights) ----
        fx2 q[8], kk[8], vv[8];
        #pragma unroll
        for (int e = 0; e < 8; ++e) {
            fx2 aq = bc(0.f), ak = bc(0.f), av = bc(0.f);
            #pragma unroll
            for (int d = 0; d < 8; ++d) {
                aq += h[d] * bc(Wq[w64 + e*8 + d]);
                ak += h[d] * bc(Wk[w64 + e*8 + d]);
                av += h[d] * bc(Wv[w64 + e*8 + d]);
            }
            q[e] = aq * bc(QSCALE); kk[e] = ak; vv[e] = av;
        }
        {   // K pairs then V pairs, interleaved [kA0,kB0,kA1,kB1,...]
            float* kvp = kvw + t * KVSTRIDE;
            *reinterpret_cast<float4*>(kvp +  0) = make_float4(kk[0].x,kk[0].y,kk[1].x,kk[1].y);
            *reinterpret_cast<float4*>(kvp +  4) = make_float4(kk[2].x,kk[2].y,kk[3].x,kk[3].y);
            *reinterpret_cast<float4*>(kvp +  8) = make_float4(kk[4].x,kk[4].y,kk[5].x,kk[5].y);
            *reinterpret_cast<float4*>(kvp + 12) = make_float4(kk[6].x,kk[6].y,kk[7].x,kk[7].y);
            *reinterpret_cast<float4*>(kvp + 16) = make_float4(vv[0].x,vv[0].y,vv[1].x,vv[1].y);
            *reinterpret_cast<float4*>(kvp + 20) = make_float4(vv[2].x,vv[2].y,vv[3].x,vv[3].y);
            *reinterpret_cast<float4*>(kvp + 24) = make_float4(vv[4].x,vv[4].y,vv[5].x,vv[5].y);
            *reinterpret_cast<float4*>(kvp + 28) = make_float4(vv[6].x,vv[6].y,vv[7].x,vv[7].y);
        }

        // ---- attention: fully unrolled s-loop, 4 accumulator banks ----
        fx2 l0b[4], l1b[4], accb[4][8];
        #pragma unroll
        for (int b = 0; b < 4; ++b) {
            l0b[b] = bc(0.f); l1b[b] = bc(0.f);
            #pragma unroll
            for (int d = 0; d < 8; ++d) accb[b][d] = bc(0.f);
        }
        #pragma unroll
        for (int s = 0; s < T_TOK; ++s) {
            const int bk = s & 3;                 // static under full unroll
            const float* sp = kvw + s * KVSTRIDE;
            float4 k01 = *reinterpret_cast<const float4*>(sp +  0);
            float4 k23 = *reinterpret_cast<const float4*>(sp +  4);
            float4 k45 = *reinterpret_cast<const float4*>(sp +  8);
            float4 k67 = *reinterpret_cast<const float4*>(sp + 12);
            fx2 d0 = q[0]*lo4(k01) + q[1]*hi4(k01) + q[2]*lo4(k23) + q[3]*hi4(k23);
            fx2 d1 = q[4]*lo4(k45) + q[5]*hi4(k45) + q[6]*lo4(k67) + q[7]*hi4(k67);
            fx2 p0 = expboth(d0), p1 = expboth(d1);
            l0b[bk] += p0; l1b[bk] += p1;
            float4 v01 = *reinterpret_cast<const float4*>(sp + 16);
            float4 v23 = *reinterpret_cast<const float4*>(sp + 20);
            float4 v45 = *reinterpret_cast<const float4*>(sp + 24);
            float4 v67 = *reinterpret_cast<const float4*>(sp + 28);
            accb[bk][0] += p0*lo4(v01); accb[bk][1] += p0*hi4(v01);
            accb[bk][2] += p0*lo4(v23); accb[bk][3] += p0*hi4(v23);
            accb[bk][4] += p1*lo4(v45); accb[bk][5] += p1*hi4(v45);
            accb[bk][6] += p1*lo4(v67); accb[bk][7] += p1*hi4(v67);
        }
        fx2 o[8];
        {
            fx2 l0 = (l0b[0] + l0b[1]) + (l0b[2] + l0b[3]);
            fx2 l1 = (l1b[0] + l1b[1]) + (l1b[2] + l1b[3]);
            const float r0A = 1.f / l0.x, r0B = 1.f / l0.y;
            const float r1A = 1.f / l1.x, r1B = 1.f / l1.y;
            #pragma unroll
            for (int d = 0; d < 4; ++d) {
                fx2 a = (accb[0][d]   + accb[1][d])   + (accb[2][d]   + accb[3][d]);
                fx2 b = (accb[0][d+4] + accb[1][d+4]) + (accb[2][d+4] + accb[3][d+4]);
                o[d]   = (fx2){a.x * r0A, a.y * r0B};
                o[d+4] = (fx2){b.x * r1A, b.y * r1B};
            }
        }

        // ---- proj + residual ----
        fx2 xn[8];
        #pragma unroll
        for (int e = 0; e < 8; ++e) {
            fx2 a = bc(Pb[w8 + e]);
            #pragma unroll
            for (int d = 0; d < 8; ++d) a += o[d] * bc(Pw[w64 + e*8 + d]);
            xn[e] = x[e] + a;
        }

        // ---- LN2 ----
        fx2 h2[8];
        {
            fx2 mu = xn[0];
            #pragma unroll
            for (int d = 1; d < 8; ++d) mu += xn[d];
            mu *= bc(0.125f);
            fx2 var = bc(0.f);
            #pragma unroll
            for (int d = 0; d < 8; ++d) { fx2 dd = xn[d] - mu; var += dd * dd; }
            var = var * bc(0.125f) + bc(1e-5f);
            fx2 rs = {rsqrtf(var.x), rsqrtf(var.y)};
            #pragma unroll
            for (int d = 0; d < 8; ++d)
                h2[d] = (xn[d] - mu) * rs * bc(g2[w8 + d]) + bc(be2[w8 + d]);
        }

        // ---- FF: 2 accumulator banks (static f&1 under full unroll) ----
        {
            fx2 accf[2][8];
            #pragma unroll
            for (int d = 0; d < 8; ++d) { accf[0][d] = bc(0.f); accf[1][d] = bc(0.f); }
            #pragma unroll
            for (int f = 0; f < 32; ++f) {
                const int bk = f & 1;
                fx2 a = bc(bb1[w32 + f]);
                #pragma unroll
                for (int d = 0; d < 8; ++d) a += h2[d] * bc(W1[w256 + f*8 + d]);
                a = fmax2(a, bc(0.f));
                #pragma unroll
                for (int d = 0; d < 8; ++d) accf[bk][d] += a * bc(W2[w256 + d*32 + f]);
            }
            #pragma unroll
            for (int d = 0; d < 8; ++d)
                x[d] = xn[d] + (accf[0][d] + accf[1][d]) + bc(bb2[w8 + d]);
        }
    }

    // ---- classification head: lane 0 (token 0), both images ----
    if (lane == 0) {
        fx2 lg[10]; fx2 mx = bc(-1e30f);
        #pragma unroll
        for (int c = 0; c < 10; ++c) {
            fx2 a = bc(mlpb[c]);
            #pragma unroll
            for (int d = 0; d < 8; ++d) a += x[d] * bc(mlpW[c*8 + d]);
            lg[c] = a; mx = fmax2(mx, a);
        }
        fx2 ssum = bc(0.f);
        #pragma unroll
        for (int c = 0; c < 10; ++c) {
            fx2 e = lg[c] - mx;
            lg[c] = (fx2){__expf(e.x), __expf(e.y)};
            ssum += lg[c];
        }
        const float rA = 1.f / ssum.x, rB = 1.f / ssum.y;
        #pragma unroll
        for (int c = 0; c < 10; ++c) {
            out[(size_t)gA*10 + c] = lg[c].x * rA;
            if (hasB) out[(size_t)gB*10 + c] = lg[c].y * rB;
        }
    }
}

extern "C" void kernel_launch(void* const* d_in, const int* in_sizes, int n_in,
                              void* d_out, int out_size, void* d_ws, size_t ws_size,
                              hipStream_t stream) {
    const int B = in_sizes[0] / 784;
    const int pairs = (B + 1) / 2;
    const int nblk = (pairs + WAVES_PB - 1) / WAVES_PB;
    vit_fwd<<<nblk, THREADS, 0, stream>>>(
        (const float*)d_in[0],  (const float*)d_in[1],  (const float*)d_in[2],
        (const float*)d_in[3],  (const float*)d_in[4],  (const float*)d_in[5],
        (const float*)d_in[6],  (const float*)d_in[7],  (const float*)d_in[8],
        (const float*)d_in[9],  (const float*)d_in[10], (const float*)d_in[11],
        (const float*)d_in[12], (const float*)d_in[13], (const float*)d_in[14],
        (const float*)d_in[15], (const float*)d_in[16], (const float*)d_in[17],
        (float*)d_out, B);
}

// Round 10
// 101.656 us; speedup vs baseline: 1.2321x; 1.1308x over previous
//
#include <hip/hip_runtime.h>

// Tiny ViT forward, B=8192, fp32. R6 structure (best measured: 97.7us):
// wave-per-IMAGE-PAIR packed in fx2 halves, per-wave LDS K/V (broadcast
// reads, zero barriers), s_load weights, one-pass softmax (no max sub).
// R10 delta vs R6: attention s-loop steps by 2 with INDEPENDENT even/odd
// accumulator banks (runtime loop, small code footprint -- R9 showed full
// unroll thrashes I-fetch), and rcpf for the softmax divides.

typedef float fx2 __attribute__((ext_vector_type(2)));

#define T_TOK    50
#define WAVES_PB 4
#define THREADS  (WAVES_PB * 64)
#define KVSTRIDE 36                  // floats per token: 32 + 4 pad
#define SCALE    0.35355339059327373f   // 8^-0.5

#if __has_builtin(__builtin_amdgcn_exp2f)
  #define FASTEXP(x) __builtin_amdgcn_exp2f(x)
  #define QSCALE (SCALE * 1.4426950408889634f)   // fold log2(e) into q
#else
  #define FASTEXP(x) __expf(x)
  #define QSCALE SCALE
#endif

__device__ __forceinline__ fx2 bc(float s)    { return (fx2){s, s}; }
__device__ __forceinline__ fx2 lo4(float4 u)  { return (fx2){u.x, u.y}; }
__device__ __forceinline__ fx2 hi4(float4 u)  { return (fx2){u.z, u.w}; }
__device__ __forceinline__ fx2 fmax2(fx2 a, fx2 b) {
    return (fx2){fmaxf(a.x, b.x), fmaxf(a.y, b.y)};
}
__device__ __forceinline__ fx2 expboth(fx2 v) {
    return (fx2){FASTEXP(v.x), FASTEXP(v.y)};
}

__global__ __launch_bounds__(THREADS) void vit_fwd(
    const float* __restrict__ images, const float* __restrict__ cls,
    const float* __restrict__ linW,
    const float* __restrict__ g1,  const float* __restrict__ be1,
    const float* __restrict__ Wq,  const float* __restrict__ Wk,
    const float* __restrict__ Wv,  const float* __restrict__ Pw,
    const float* __restrict__ Pb,  const float* __restrict__ g2,
    const float* __restrict__ be2, const float* __restrict__ W1,
    const float* __restrict__ bb1, const float* __restrict__ W2,
    const float* __restrict__ bb2, const float* __restrict__ mlpW,
    const float* __restrict__ mlpb,
    float* __restrict__ out, int B)
{
    __shared__ float kv[WAVES_PB * T_TOK * KVSTRIDE];   // 28800 B

    const int lane = threadIdx.x & 63;
    const int wid  = threadIdx.x >> 6;
    const int pair = blockIdx.x * WAVES_PB + wid;   // wave-uniform
    const int gA   = pair * 2;
    if (gA >= B) return;
    const bool hasB = (gA + 1) < B;
    const int gB   = hasB ? gA + 1 : gA;
    const int t    = (lane < T_TOK) ? lane : (T_TOK - 1);
    float* __restrict__ kvw = kv + wid * (T_TOK * KVSTRIDE);

    // ---- patch embed + positional (pos depends only on t: shared) ----
    fx2 x[8];
    {
        const float FR[4] = {1.f, 0.1f, 0.01f, 0.001f};
        float pos[8];
        #pragma unroll
        for (int j = 0; j < 8; ++j) {
            float arg = (float)t * FR[j >> 1];
            pos[j] = (j & 1) ? __cosf(arg) : __sinf(arg);
        }
        if (t == 0) {
            #pragma unroll
            for (int e = 0; e < 8; ++e) x[e] = bc(cls[e] + pos[e]);
        } else {
            const int p = t - 1, pr = p / 7, pc = p - pr * 7;
            const size_t off = (size_t)pr * 112 + pc * 4;
            const float* ibA = images + (size_t)gA * 784 + off;
            const float* ibB = images + (size_t)gB * 784 + off;
            fx2 pf[16];
            #pragma unroll
            for (int r = 0; r < 4; ++r) {
                float4 ua = *reinterpret_cast<const float4*>(ibA + r * 28);
                float4 ub = *reinterpret_cast<const float4*>(ibB + r * 28);
                pf[r*4+0] = (fx2){ua.x, ub.x}; pf[r*4+1] = (fx2){ua.y, ub.y};
                pf[r*4+2] = (fx2){ua.z, ub.z}; pf[r*4+3] = (fx2){ua.w, ub.w};
            }
            #pragma unroll
            for (int e = 0; e < 8; ++e) {
                fx2 a = bc(pos[e]);
                #pragma unroll
                for (int i = 0; i < 16; ++i) a += pf[i] * bc(linW[e*16 + i]);
                x[e] = a;
            }
        }
    }

    #pragma unroll 1
    for (int blk = 0; blk < 4; ++blk) {
        const int w8 = blk * 8, w64 = blk * 64, w256 = blk * 256, w32 = blk * 32;

        // ---- LN1 ----
        fx2 h[8];
        {
            fx2 mu = x[0];
            #pragma unroll
            for (int d = 1; d < 8; ++d) mu += x[d];
            mu *= bc(0.125f);
            fx2 var = bc(0.f);
            #pragma unroll
            for (int d = 0; d < 8; ++d) { fx2 dd = x[d] - mu; var += dd * dd; }
            var = var * bc(0.125f) + bc(1e-5f);
            fx2 rs = {rsqrtf(var.x), rsqrtf(var.y)};
            #pragma unroll
            for (int d = 0; d < 8; ++d)
                h[d] = (x[d] - mu) * rs * bc(g1[w8 + d]) + bc(be1[w8 + d]);
        }

        // ---- q,k,v: packed pk_fma chains (SGPR-broadcast weights) ----
        fx2 q[8], kk[8], vv[8];
        #pragma unroll
        for (int e = 0; e < 8; ++e) {
            fx2 aq = bc(0.f), ak = bc(0.f), av = bc(0.f);
            #pragma unroll
            for (int d = 0; d < 8; ++d) {
                aq += h[d] * bc(Wq[w64 + e*8 + d]);
                ak += h[d] * bc(Wk[w64 + e*8 + d]);
                av += h[d] * bc(Wv[w64 + e*8 + d]);
            }
            q[e] = aq * bc(QSCALE); kk[e] = ak; vv[e] = av;
        }
        {   // K pairs then V pairs, interleaved [kA0,kB0,kA1,kB1,...]
            float* kvp = kvw + t * KVSTRIDE;
            *reinterpret_cast<float4*>(kvp +  0) = make_float4(kk[0].x,kk[0].y,kk[1].x,kk[1].y);
            *reinterpret_cast<float4*>(kvp +  4) = make_float4(kk[2].x,kk[2].y,kk[3].x,kk[3].y);
            *reinterpret_cast<float4*>(kvp +  8) = make_float4(kk[4].x,kk[4].y,kk[5].x,kk[5].y);
            *reinterpret_cast<float4*>(kvp + 12) = make_float4(kk[6].x,kk[6].y,kk[7].x,kk[7].y);
            *reinterpret_cast<float4*>(kvp + 16) = make_float4(vv[0].x,vv[0].y,vv[1].x,vv[1].y);
            *reinterpret_cast<float4*>(kvp + 20) = make_float4(vv[2].x,vv[2].y,vv[3].x,vv[3].y);
            *reinterpret_cast<float4*>(kvp + 24) = make_float4(vv[4].x,vv[4].y,vv[5].x,vv[5].y);
            *reinterpret_cast<float4*>(kvp + 28) = make_float4(vv[6].x,vv[6].y,vv[7].x,vv[7].y);
        }

        // ---- attention: step-2 s-loop, independent even/odd banks ----
        fx2 l0e = {0,0}, l1e = {0,0}, l0o = {0,0}, l1o = {0,0};
        fx2 ace[8], aco[8];
        #pragma unroll
        for (int d = 0; d < 8; ++d) { ace[d] = (fx2){0,0}; aco[d] = (fx2){0,0}; }
        #pragma unroll 2
        for (int s = 0; s < T_TOK; s += 2) {
            const float* sp0 = kvw + s * KVSTRIDE;
            const float* sp1 = sp0 + KVSTRIDE;
            float4 ek01 = *reinterpret_cast<const float4*>(sp0 +  0);
            float4 ek23 = *reinterpret_cast<const float4*>(sp0 +  4);
            float4 ek45 = *reinterpret_cast<const float4*>(sp0 +  8);
            float4 ek67 = *reinterpret_cast<const float4*>(sp0 + 12);
            float4 ok01 = *reinterpret_cast<const float4*>(sp1 +  0);
            float4 ok23 = *reinterpret_cast<const float4*>(sp1 +  4);
            float4 ok45 = *reinterpret_cast<const float4*>(sp1 +  8);
            float4 ok67 = *reinterpret_cast<const float4*>(sp1 + 12);
            fx2 de0 = q[0]*lo4(ek01) + q[1]*hi4(ek01) + q[2]*lo4(ek23) + q[3]*hi4(ek23);
            fx2 de1 = q[4]*lo4(ek45) + q[5]*hi4(ek45) + q[6]*lo4(ek67) + q[7]*hi4(ek67);
            fx2 do0 = q[0]*lo4(ok01) + q[1]*hi4(ok01) + q[2]*lo4(ok23) + q[3]*hi4(ok23);
            fx2 do1 = q[4]*lo4(ok45) + q[5]*hi4(ok45) + q[6]*lo4(ok67) + q[7]*hi4(ok67);
            fx2 pe0 = expboth(de0), pe1 = expboth(de1);
            fx2 po0 = expboth(do0), po1 = expboth(do1);
            l0e += pe0; l1e += pe1; l0o += po0; l1o += po1;
            float4 ev01 = *reinterpret_cast<const float4*>(sp0 + 16);
            float4 ev23 = *reinterpret_cast<const float4*>(sp0 + 20);
            float4 ev45 = *reinterpret_cast<const float4*>(sp0 + 24);
            float4 ev67 = *reinterpret_cast<const float4*>(sp0 + 28);
            float4 ov01 = *reinterpret_cast<const float4*>(sp1 + 16);
            float4 ov23 = *reinterpret_cast<const float4*>(sp1 + 20);
            float4 ov45 = *reinterpret_cast<const float4*>(sp1 + 24);
            float4 ov67 = *reinterpret_cast<const float4*>(sp1 + 28);
            ace[0] += pe0*lo4(ev01); ace[1] += pe0*hi4(ev01);
            ace[2] += pe0*lo4(ev23); ace[3] += pe0*hi4(ev23);
            ace[4] += pe1*lo4(ev45); ace[5] += pe1*hi4(ev45);
            ace[6] += pe1*lo4(ev67); ace[7] += pe1*hi4(ev67);
            aco[0] += po0*lo4(ov01); aco[1] += po0*hi4(ov01);
            aco[2] += po0*lo4(ov23); aco[3] += po0*hi4(ov23);
            aco[4] += po1*lo4(ov45); aco[5] += po1*hi4(ov45);
            aco[6] += po1*lo4(ov67); aco[7] += po1*hi4(ov67);
        }
        fx2 o[8];
        {
            fx2 l0 = l0e + l0o, l1 = l1e + l1o;
            const float r0A = __builtin_amdgcn_rcpf(l0.x);
            const float r0B = __builtin_amdgcn_rcpf(l0.y);
            const float r1A = __builtin_amdgcn_rcpf(l1.x);
            const float r1B = __builtin_amdgcn_rcpf(l1.y);
            #pragma unroll
            for (int d = 0; d < 4; ++d) {
                fx2 a = ace[d] + aco[d];
                fx2 b = ace[d+4] + aco[d+4];
                o[d]   = (fx2){a.x * r0A, a.y * r0B};
                o[d+4] = (fx2){b.x * r1A, b.y * r1B};
            }
        }

        // ---- proj + residual ----
        fx2 xn[8];
        #pragma unroll
        for (int e = 0; e < 8; ++e) {
            fx2 a = bc(Pb[w8 + e]);
            #pragma unroll
            for (int d = 0; d < 8; ++d) a += o[d] * bc(Pw[w64 + e*8 + d]);
            xn[e] = x[e] + a;
        }

        // ---- LN2 ----
        fx2 h2[8];
        {
            fx2 mu = xn[0];
            #pragma unroll
            for (int d = 1; d < 8; ++d) mu += xn[d];
            mu *= bc(0.125f);
            fx2 var = bc(0.f);
            #pragma unroll
            for (int d = 0; d < 8; ++d) { fx2 dd = xn[d] - mu; var += dd * dd; }
            var = var * bc(0.125f) + bc(1e-5f);
            fx2 rs = {rsqrtf(var.x), rsqrtf(var.y)};
            #pragma unroll
            for (int d = 0; d < 8; ++d)
                h2[d] = (xn[d] - mu) * rs * bc(g2[w8 + d]) + bc(be2[w8 + d]);
        }

        // ---- FF ----
        {
            fx2 accf[2][8];
            #pragma unroll
            for (int d = 0; d < 8; ++d) { accf[0][d] = bc(0.f); accf[1][d] = bc(0.f); }
            #pragma unroll 4
            for (int f = 0; f < 32; ++f) {
                const int bk = f & 1;
                fx2 a = bc(bb1[w32 + f]);
                #pragma unroll
                for (int d = 0; d < 8; ++d) a += h2[d] * bc(W1[w256 + f*8 + d]);
                a = fmax2(a, bc(0.f));
                #pragma unroll
                for (int d = 0; d < 8; ++d) accf[bk][d] += a * bc(W2[w256 + d*32 + f]);
            }
            #pragma unroll
            for (int d = 0; d < 8; ++d)
                x[d] = xn[d] + (accf[0][d] + accf[1][d]) + bc(bb2[w8 + d]);
        }
    }

    // ---- classification head: lane 0 (token 0), both images ----
    if (lane == 0) {
        fx2 lg[10]; fx2 mx = bc(-1e30f);
        #pragma unroll
        for (int c = 0; c < 10; ++c) {
            fx2 a = bc(mlpb[c]);
            #pragma unroll
            for (int d = 0; d < 8; ++d) a += x[d] * bc(mlpW[c*8 + d]);
            lg[c] = a; mx = fmax2(mx, a);
        }
        fx2 ssum = bc(0.f);
        #pragma unroll
        for (int c = 0; c < 10; ++c) {
            fx2 e = lg[c] - mx;
            lg[c] = (fx2){__expf(e.x), __expf(e.y)};
            ssum += lg[c];
        }
        const float rA = 1.f / ssum.x, rB = 1.f / ssum.y;
        #pragma unroll
        for (int c = 0; c < 10; ++c) {
            out[(size_t)gA*10 + c] = lg[c].x * rA;
            if (hasB) out[(size_t)gB*10 + c] = lg[c].y * rB;
        }
    }
}

extern "C" void kernel_launch(void* const* d_in, const int* in_sizes, int n_in,
                              void* d_out, int out_size, void* d_ws, size_t ws_size,
                              hipStream_t stream) {
    const int B = in_sizes[0] / 784;
    const int pairs = (B + 1) / 2;
    const int nblk = (pairs + WAVES_PB - 1) / WAVES_PB;
    vit_fwd<<<nblk, THREADS, 0, stream>>>(
        (const float*)d_in[0],  (const float*)d_in[1],  (const float*)d_in[2],
        (const float*)d_in[3],  (const float*)d_in[4],  (const float*)d_in[5],
        (const float*)d_in[6],  (const float*)d_in[7],  (const float*)d_in[8],
        (const float*)d_in[9],  (const float*)d_in[10], (const float*)d_in[11],
        (const float*)d_in[12], (const float*)d_in[13], (const float*)d_in[14],
        (const float*)d_in[15], (const float*)d_in[16], (const float*)d_in[17],
        (float*)d_out, B);
}

// Round 11
// 98.398 us; speedup vs baseline: 1.2729x; 1.0331x over previous
//
#include <hip/hip_runtime.h>

// Tiny ViT forward, B=8192, fp32. R6 structure (best measured: 97.7us):
// wave-per-IMAGE-PAIR packed in fx2 halves, per-wave LDS K/V (broadcast
// reads, zero barriers), s_load weights, one-pass softmax (no max sub).
// R11 delta vs R6 (single variable): attention s-loop uses an explicit
// register DOUBLE-BUFFER (b0/b1 rotation) so each 8x ds_read batch is
// issued one full compute body before first use -- targets the
// loop-carried lgkmcnt stall that 4 waves/SIMD cannot hide.

typedef float fx2 __attribute__((ext_vector_type(2)));

#define T_TOK    50
#define WAVES_PB 4
#define THREADS  (WAVES_PB * 64)
#define KVSTRIDE 36                  // floats per token: 32 + 4 pad
#define SCALE    0.35355339059327373f   // 8^-0.5

#if __has_builtin(__builtin_amdgcn_exp2f)
  #define FASTEXP(x) __builtin_amdgcn_exp2f(x)
  #define QSCALE (SCALE * 1.4426950408889634f)   // fold log2(e) into q
#else
  #define FASTEXP(x) __expf(x)
  #define QSCALE SCALE
#endif

__device__ __forceinline__ fx2 bc(float s)    { return (fx2){s, s}; }
__device__ __forceinline__ fx2 lo4(float4 u)  { return (fx2){u.x, u.y}; }
__device__ __forceinline__ fx2 hi4(float4 u)  { return (fx2){u.z, u.w}; }
__device__ __forceinline__ fx2 fmax2(fx2 a, fx2 b) {
    return (fx2){fmaxf(a.x, b.x), fmaxf(a.y, b.y)};
}
__device__ __forceinline__ fx2 expboth(fx2 v) {
    return (fx2){FASTEXP(v.x), FASTEXP(v.y)};
}

__global__ __launch_bounds__(THREADS) void vit_fwd(
    const float* __restrict__ images, const float* __restrict__ cls,
    const float* __restrict__ linW,
    const float* __restrict__ g1,  const float* __restrict__ be1,
    const float* __restrict__ Wq,  const float* __restrict__ Wk,
    const float* __restrict__ Wv,  const float* __restrict__ Pw,
    const float* __restrict__ Pb,  const float* __restrict__ g2,
    const float* __restrict__ be2, const float* __restrict__ W1,
    const float* __restrict__ bb1, const float* __restrict__ W2,
    const float* __restrict__ bb2, const float* __restrict__ mlpW,
    const float* __restrict__ mlpb,
    float* __restrict__ out, int B)
{
    __shared__ float kv[WAVES_PB * T_TOK * KVSTRIDE];   // 28800 B

    const int lane = threadIdx.x & 63;
    const int wid  = threadIdx.x >> 6;
    const int pair = blockIdx.x * WAVES_PB + wid;   // wave-uniform
    const int gA   = pair * 2;
    if (gA >= B) return;
    const bool hasB = (gA + 1) < B;
    const int gB   = hasB ? gA + 1 : gA;
    const int t    = (lane < T_TOK) ? lane : (T_TOK - 1);
    float* __restrict__ kvw = kv + wid * (T_TOK * KVSTRIDE);

    // ---- patch embed + positional (pos depends only on t: shared) ----
    fx2 x[8];
    {
        const float FR[4] = {1.f, 0.1f, 0.01f, 0.001f};
        float pos[8];
        #pragma unroll
        for (int j = 0; j < 8; ++j) {
            float arg = (float)t * FR[j >> 1];
            pos[j] = (j & 1) ? __cosf(arg) : __sinf(arg);
        }
        if (t == 0) {
            #pragma unroll
            for (int e = 0; e < 8; ++e) x[e] = bc(cls[e] + pos[e]);
        } else {
            const int p = t - 1, pr = p / 7, pc = p - pr * 7;
            const size_t off = (size_t)pr * 112 + pc * 4;
            const float* ibA = images + (size_t)gA * 784 + off;
            const float* ibB = images + (size_t)gB * 784 + off;
            fx2 pf[16];
            #pragma unroll
            for (int r = 0; r < 4; ++r) {
                float4 ua = *reinterpret_cast<const float4*>(ibA + r * 28);
                float4 ub = *reinterpret_cast<const float4*>(ibB + r * 28);
                pf[r*4+0] = (fx2){ua.x, ub.x}; pf[r*4+1] = (fx2){ua.y, ub.y};
                pf[r*4+2] = (fx2){ua.z, ub.z}; pf[r*4+3] = (fx2){ua.w, ub.w};
            }
            #pragma unroll
            for (int e = 0; e < 8; ++e) {
                fx2 a = bc(pos[e]);
                #pragma unroll
                for (int i = 0; i < 16; ++i) a += pf[i] * bc(linW[e*16 + i]);
                x[e] = a;
            }
        }
    }

    #pragma unroll 1
    for (int blk = 0; blk < 4; ++blk) {
        const int w8 = blk * 8, w64 = blk * 64, w256 = blk * 256, w32 = blk * 32;

        // ---- LN1 ----
        fx2 h[8];
        {
            fx2 mu = x[0];
            #pragma unroll
            for (int d = 1; d < 8; ++d) mu += x[d];
            mu *= bc(0.125f);
            fx2 var = bc(0.f);
            #pragma unroll
            for (int d = 0; d < 8; ++d) { fx2 dd = x[d] - mu; var += dd * dd; }
            var = var * bc(0.125f) + bc(1e-5f);
            fx2 rs = {rsqrtf(var.x), rsqrtf(var.y)};
            #pragma unroll
            for (int d = 0; d < 8; ++d)
                h[d] = (x[d] - mu) * rs * bc(g1[w8 + d]) + bc(be1[w8 + d]);
        }

        // ---- q,k,v: packed pk_fma chains (SGPR-broadcast weights) ----
        fx2 q[8], kk[8], vv[8];
        #pragma unroll
        for (int e = 0; e < 8; ++e) {
            fx2 aq = bc(0.f), ak = bc(0.f), av = bc(0.f);
            #pragma unroll
            for (int d = 0; d < 8; ++d) {
                aq += h[d] * bc(Wq[w64 + e*8 + d]);
                ak += h[d] * bc(Wk[w64 + e*8 + d]);
                av += h[d] * bc(Wv[w64 + e*8 + d]);
            }
            q[e] = aq * bc(QSCALE); kk[e] = ak; vv[e] = av;
        }
        {   // K pairs then V pairs, interleaved [kA0,kB0,kA1,kB1,...]
            float* kvp = kvw + t * KVSTRIDE;
            *reinterpret_cast<float4*>(kvp +  0) = make_float4(kk[0].x,kk[0].y,kk[1].x,kk[1].y);
            *reinterpret_cast<float4*>(kvp +  4) = make_float4(kk[2].x,kk[2].y,kk[3].x,kk[3].y);
            *reinterpret_cast<float4*>(kvp +  8) = make_float4(kk[4].x,kk[4].y,kk[5].x,kk[5].y);
            *reinterpret_cast<float4*>(kvp + 12) = make_float4(kk[6].x,kk[6].y,kk[7].x,kk[7].y);
            *reinterpret_cast<float4*>(kvp + 16) = make_float4(vv[0].x,vv[0].y,vv[1].x,vv[1].y);
            *reinterpret_cast<float4*>(kvp + 20) = make_float4(vv[2].x,vv[2].y,vv[3].x,vv[3].y);
            *reinterpret_cast<float4*>(kvp + 24) = make_float4(vv[4].x,vv[4].y,vv[5].x,vv[5].y);
            *reinterpret_cast<float4*>(kvp + 28) = make_float4(vv[6].x,vv[6].y,vv[7].x,vv[7].y);
        }

        // ---- attention: register double-buffered s-loop ----
        fx2 l0 = {0,0}, l1 = {0,0};
        fx2 acc[8];
        #pragma unroll
        for (int d = 0; d < 8; ++d) acc[d] = (fx2){0,0};

        float4 b0[8], b1[8];
        #pragma unroll
        for (int i = 0; i < 8; ++i)
            b0[i] = *reinterpret_cast<const float4*>(kvw + i * 4);   // s=0

        auto att_step = [&](const float4* buf) {
            fx2 d0 = q[0]*lo4(buf[0]) + q[1]*hi4(buf[0])
                   + q[2]*lo4(buf[1]) + q[3]*hi4(buf[1]);
            fx2 d1 = q[4]*lo4(buf[2]) + q[5]*hi4(buf[2])
                   + q[6]*lo4(buf[3]) + q[7]*hi4(buf[3]);
            fx2 p0 = expboth(d0), p1 = expboth(d1);
            l0 += p0; l1 += p1;
            acc[0] += p0*lo4(buf[4]); acc[1] += p0*hi4(buf[4]);
            acc[2] += p0*lo4(buf[5]); acc[3] += p0*hi4(buf[5]);
            acc[4] += p1*lo4(buf[6]); acc[5] += p1*hi4(buf[6]);
            acc[6] += p1*lo4(buf[7]); acc[7] += p1*hi4(buf[7]);
        };

        #pragma unroll 1
        for (int s = 0; s < T_TOK; s += 2) {
            {   // load s+1 into b1 (s+1 <= 49 always)
                const float* sp = kvw + (s + 1) * KVSTRIDE;
                #pragma unroll
                for (int i = 0; i < 8; ++i)
                    b1[i] = *reinterpret_cast<const float4*>(sp + i * 4);
            }
            att_step(b0);
            {   // load s+2 (clamped; final redundant load is harmless)
                const int s2 = (s + 2 < T_TOK) ? (s + 2) : (T_TOK - 1);
                const float* sp = kvw + s2 * KVSTRIDE;
                #pragma unroll
                for (int i = 0; i < 8; ++i)
                    b0[i] = *reinterpret_cast<const float4*>(sp + i * 4);
            }
            att_step(b1);
        }

        fx2 o[8];
        {
            const float r0A = 1.f / l0.x, r0B = 1.f / l0.y;
            const float r1A = 1.f / l1.x, r1B = 1.f / l1.y;
            #pragma unroll
            for (int d = 0; d < 4; ++d) {
                o[d]   = (fx2){acc[d].x   * r0A, acc[d].y   * r0B};
                o[d+4] = (fx2){acc[d+4].x * r1A, acc[d+4].y * r1B};
            }
        }

        // ---- proj + residual ----
        fx2 xn[8];
        #pragma unroll
        for (int e = 0; e < 8; ++e) {
            fx2 a = bc(Pb[w8 + e]);
            #pragma unroll
            for (int d = 0; d < 8; ++d) a += o[d] * bc(Pw[w64 + e*8 + d]);
            xn[e] = x[e] + a;
        }

        // ---- LN2 ----
        fx2 h2[8];
        {
            fx2 mu = xn[0];
            #pragma unroll
            for (int d = 1; d < 8; ++d) mu += xn[d];
            mu *= bc(0.125f);
            fx2 var = bc(0.f);
            #pragma unroll
            for (int d = 0; d < 8; ++d) { fx2 dd = xn[d] - mu; var += dd * dd; }
            var = var * bc(0.125f) + bc(1e-5f);
            fx2 rs = {rsqrtf(var.x), rsqrtf(var.y)};
            #pragma unroll
            for (int d = 0; d < 8; ++d)
                h2[d] = (xn[d] - mu) * rs * bc(g2[w8 + d]) + bc(be2[w8 + d]);
        }

        // ---- FF (R6 form: f-pairs, single acc set) ----
        {
            fx2 acc2[8];
            #pragma unroll
            for (int d = 0; d < 8; ++d) acc2[d] = bc(0.f);
            #pragma unroll 4
            for (int f = 0; f < 32; ++f) {
                fx2 a = bc(bb1[w32 + f]);
                #pragma unroll
                for (int d = 0; d < 8; ++d) a += h2[d] * bc(W1[w256 + f*8 + d]);
                a = fmax2(a, bc(0.f));
                #pragma unroll
                for (int d = 0; d < 8; ++d) acc2[d] += a * bc(W2[w256 + d*32 + f]);
            }
            #pragma unroll
            for (int d = 0; d < 8; ++d)
                x[d] = xn[d] + acc2[d] + bc(bb2[w8 + d]);
        }
    }

    // ---- classification head: lane 0 (token 0), both images ----
    if (lane == 0) {
        fx2 lg[10]; fx2 mx = bc(-1e30f);
        #pragma unroll
        for (int c = 0; c < 10; ++c) {
            fx2 a = bc(mlpb[c]);
            #pragma unroll
            for (int d = 0; d < 8; ++d) a += x[d] * bc(mlpW[c*8 + d]);
            lg[c] = a; mx = fmax2(mx, a);
        }
        fx2 ssum = bc(0.f);
        #pragma unroll
        for (int c = 0; c < 10; ++c) {
            fx2 e = lg[c] - mx;
            lg[c] = (fx2){__expf(e.x), __expf(e.y)};
            ssum += lg[c];
        }
        const float rA = 1.f / ssum.x, rB = 1.f / ssum.y;
        #pragma unroll
        for (int c = 0; c < 10; ++c) {
            out[(size_t)gA*10 + c] = lg[c].x * rA;
            if (hasB) out[(size_t)gB*10 + c] = lg[c].y * rB;
        }
    }
}

extern "C" void kernel_launch(void* const* d_in, const int* in_sizes, int n_in,
                              void* d_out, int out_size, void* d_ws, size_t ws_size,
                              hipStream_t stream) {
    const int B = in_sizes[0] / 784;
    const int pairs = (B + 1) / 2;
    const int nblk = (pairs + WAVES_PB - 1) / WAVES_PB;
    vit_fwd<<<nblk, THREADS, 0, stream>>>(
        (const float*)d_in[0],  (const float*)d_in[1],  (const float*)d_in[2],
        (const float*)d_in[3],  (const float*)d_in[4],  (const float*)d_in[5],
        (const float*)d_in[6],  (const float*)d_in[7],  (const float*)d_in[8],
        (const float*)d_in[9],  (const float*)d_in[10], (const float*)d_in[11],
        (const float*)d_in[12], (const float*)d_in[13], (const float*)d_in[14],
        (const float*)d_in[15], (const float*)d_in[16], (const float*)d_in[17],
        (float*)d_out, B);
}